// Round 2
// baseline (15980.090 us; speedup 1.0000x reference)
//
#include <hip/hip_runtime.h>

#define HB 64      // batch
#define HT 1024    // time
#define HI 256     // input dim
#define HH 512     // hidden dim

typedef short short8 __attribute__((ext_vector_type(8)));
typedef float f32x4 __attribute__((ext_vector_type(4)));

__device__ __forceinline__ unsigned short f2bf(float f) {
    unsigned u = __float_as_uint(f);
    u += 0x7FFF + ((u >> 16) & 1);          // round-to-nearest-even
    return (unsigned short)(u >> 16);
}

__device__ __forceinline__ float fsigmoid(float x) {
    return 1.0f / (1.0f + __expf(-x));
}
__device__ __forceinline__ float ftanh(float x) {
    // tanh(x) = 1 - 2/(e^{2x}+1); saturates correctly at +/-inf
    return 1.0f - 2.0f / (__expf(2.0f * x) + 1.0f);
}

// ---------------------------------------------------------------------------
// Pack weights to bf16 in MFMA B-fragment-linear layout (proven in round 1).
// wp layout: [nt(128)][kt][lane(64)][j(8)], elem = W[nt*16+(l&15)][kt*32+(l>>4)*8+j]
// layer0: K=768 (x 256 | h 512), 24 kt.  layer1: K=1024 (h0 512 | h1 512), 32 kt.
// bs[layer*2048 + n] = b_ih[n] + b_hh[n].
// ---------------------------------------------------------------------------
__global__ void pack_weights(const float* __restrict__ Wih0, const float* __restrict__ Whh0,
                             const float* __restrict__ bih0, const float* __restrict__ bhh0,
                             const float* __restrict__ Wih1, const float* __restrict__ Whh1,
                             const float* __restrict__ bih1, const float* __restrict__ bhh1,
                             unsigned short* __restrict__ wp0,
                             unsigned short* __restrict__ wp1,
                             float* __restrict__ bs) {
    int idx = blockIdx.x * 256 + threadIdx.x;
    int stride = gridDim.x * 256;
    const int NP0 = 128 * 24 * 512;
    const int NP1 = 128 * 32 * 512;
    for (int e = idx; e < NP0; e += stride) {
        int j = e & 7, l = (e >> 3) & 63, rem = e >> 9;
        int kt = rem % 24, nt = rem / 24;
        int n = nt * 16 + (l & 15);
        int k = kt * 32 + ((l >> 4) << 3) + j;
        float v = (k < HI) ? Wih0[n * HI + k] : Whh0[n * HH + (k - HI)];
        wp0[e] = f2bf(v);
    }
    for (int e = idx; e < NP1; e += stride) {
        int j = e & 7, l = (e >> 3) & 63, rem = e >> 9;
        int kt = rem & 31, nt = rem >> 5;
        int n = nt * 16 + (l & 15);
        int k = kt * 32 + ((l >> 4) << 3) + j;
        float v = (k < HH) ? Wih1[n * HH + k] : Whh1[n * HH + (k - HH)];
        wp1[e] = f2bf(v);
    }
    for (int e = idx; e < 2048; e += stride) {
        bs[e]        = bih0[e] + bhh0[e];
        bs[2048 + e] = bih1[e] + bhh1[e];
    }
}

// ---------------------------------------------------------------------------
// Pack x (B,1,I,T) -> bf16 A-fragment layout xp[t][mt(4)][kt(8)][lane(64)][j(8)]
// (proven in round 1)
// ---------------------------------------------------------------------------
__global__ void pack_x(const float* __restrict__ x, unsigned short* __restrict__ xp) {
    int tt = blockIdx.x;   // 64
    int ii = blockIdx.y;   // 8
    int bt = blockIdx.z;   // 4
    int w  = threadIdx.x;  // 256
    __shared__ unsigned short tile[512][16];
    int tloc = w & 15;
    for (int q = 0; q < 32; ++q) {
        int p = q * 16 + (w >> 4);
        int m = p >> 5, iloc = p & 31;
        int b = bt * 16 + m, i = ii * 32 + iloc, t = tt * 16 + tloc;
        tile[p][tloc] = f2bf(x[((size_t)b * HI + i) * HT + t]);
    }
    __syncthreads();
    int e  = w * 2;
    int l  = e >> 3, j0 = e & 7;
    int m  = l & 15;
    int i0 = ((l >> 4) << 3) + j0;
    for (int ti = 0; ti < 16; ++ti) {
        int t = tt * 16 + ti;
        size_t base = ((size_t)(t * 4 + bt) * 8 + ii) * 512;
        unsigned v0 = tile[m * 32 + i0][ti];
        unsigned v1 = tile[m * 32 + i0 + 1][ti];
        ((unsigned int*)xp)[(base + e) >> 1] = v0 | (v1 << 16);
    }
}

__global__ void init_flags(int* __restrict__ f, int n) {
    int idx = blockIdx.x * 256 + threadIdx.x;
    for (int e = idx; e < n; e += gridDim.x * 256) f[e] = 0;
}

// ---------------------------------------------------------------------------
// Persistent pipelined LSTM. 64 blocks x 256 threads, 1 block/CU (128KB LDS).
// Blocks 0..31: layer0, ut=bid.  Blocks 32..63: layer1, ut=bid-32.
// Wave w = batch tile mt. Weights LDS-resident. Cell state in registers.
// Sync: flag0[t]/flag1[t] count-to-32 release counters (agent scope).
//   flag0[t] <- {flag0[t-1], flag1[t-4]}   (h0 ring depth 4 back-pressure)
//   flag1[t] <- {flag1[t-1], flag0[t]}     (h1 ring depth 2)
// ---------------------------------------------------------------------------
__global__ void __launch_bounds__(256, 1) lstm_persist(
        const unsigned short* __restrict__ wp0,
        const unsigned short* __restrict__ wp1,
        const float* __restrict__ bs,
        const unsigned short* __restrict__ xp,
        unsigned short* __restrict__ h0ring,   // [4][mt4][kt16][64][8] bf16
        unsigned short* __restrict__ h1ring,   // [2][mt4][kt16][64][8] bf16
        int* __restrict__ flag0,
        int* __restrict__ flag1,
        float* __restrict__ out) {
    __shared__ short lds[65536];               // 128 KB

    const int bid   = blockIdx.x;
    const int layer = bid >> 5;
    const int ut    = bid & 31;
    const int tid   = threadIdx.x;
    const int mt    = tid >> 6;
    const int l     = tid & 63;
    const int ul    = l & 15;
    const int q     = l >> 4;
    const int KT    = layer ? 32 : 24;

    // ---- stage weight slice into LDS (4 gate n-tiles, contiguous chunks) ----
    {
        const unsigned short* wsrc = layer ? wp1 : wp0;
        for (int g = 0; g < 4; ++g) {
            const int4* src = (const int4*)(wsrc + (size_t)(g * 32 + ut) * KT * 512);
            int4* dst = (int4*)lds + (size_t)g * KT * 64;
            for (int i = tid; i < KT * 64; i += 256) dst[i] = src[i];
        }
    }
    float bv[4];
    #pragma unroll
    for (int g = 0; g < 4; ++g) bv[g] = bs[layer * 2048 + g * HH + ut * 16 + ul];
    float cc[4] = {0.f, 0.f, 0.f, 0.f};
    __syncthreads();

    const short8* ldsf = (const short8*)lds;
    const int u = ut * 16 + ul;
    const int la_off = ((u >> 3) & 3) << 4;
    const int hw_sub = ((u >> 5) * 512) + (u & 7);   // kt*512 + j within slot/mt

    for (int t = 0; t < HT; ++t) {
        f32x4 acc[4];
        #pragma unroll
        for (int g = 0; g < 4; ++g) {
            f32x4 a; a[0] = bv[g]; a[1] = bv[g]; a[2] = bv[g]; a[3] = bv[g];
            acc[g] = a;
        }

        if (layer == 0) {
            // x part first: no recurrent dependency, overlaps the spin below
            const short8* xa = (const short8*)xp + ((size_t)t * 4 + mt) * 8 * 64;
            #pragma unroll
            for (int kt = 0; kt < 8; ++kt) {
                short8 a = xa[kt * 64 + l];
                #pragma unroll
                for (int g = 0; g < 4; ++g)
                    acc[g] = __builtin_amdgcn_mfma_f32_16x16x32_bf16(
                        a, ldsf[(g * 24 + kt) * 64 + l], acc[g], 0, 0, 0);
            }
            if (t > 0) {
                if (tid == 0) {
                    while (__hip_atomic_load(&flag0[t - 1], __ATOMIC_RELAXED,
                                             __HIP_MEMORY_SCOPE_AGENT) < 32)
                        __builtin_amdgcn_s_sleep(1);
                    if (t >= 4)
                        while (__hip_atomic_load(&flag1[t - 4], __ATOMIC_RELAXED,
                                                 __HIP_MEMORY_SCOPE_AGENT) < 32)
                            __builtin_amdgcn_s_sleep(1);
                }
                __syncthreads();
                __builtin_amdgcn_fence(__ATOMIC_ACQUIRE, "agent");
                const short8* ha = (const short8*)h0ring +
                                   ((size_t)(((t - 1) & 3) * 4 + mt) * 16) * 64;
                #pragma unroll
                for (int kt = 0; kt < 16; ++kt) {
                    short8 a = ha[kt * 64 + l];
                    #pragma unroll
                    for (int g = 0; g < 4; ++g)
                        acc[g] = __builtin_amdgcn_mfma_f32_16x16x32_bf16(
                            a, ldsf[(g * 24 + 8 + kt) * 64 + l], acc[g], 0, 0, 0);
                }
            }
        } else {
            // recurrent half first (flag1[t-1]), then input half (flag0[t])
            if (t > 0) {
                if (tid == 0)
                    while (__hip_atomic_load(&flag1[t - 1], __ATOMIC_RELAXED,
                                             __HIP_MEMORY_SCOPE_AGENT) < 32)
                        __builtin_amdgcn_s_sleep(1);
                __syncthreads();
                __builtin_amdgcn_fence(__ATOMIC_ACQUIRE, "agent");
                const short8* ha = (const short8*)h1ring +
                                   ((size_t)(((t - 1) & 1) * 4 + mt) * 16) * 64;
                #pragma unroll
                for (int kt = 0; kt < 16; ++kt) {
                    short8 a = ha[kt * 64 + l];
                    #pragma unroll
                    for (int g = 0; g < 4; ++g)
                        acc[g] = __builtin_amdgcn_mfma_f32_16x16x32_bf16(
                            a, ldsf[(g * 32 + 16 + kt) * 64 + l], acc[g], 0, 0, 0);
                }
            }
            if (tid == 0)
                while (__hip_atomic_load(&flag0[t], __ATOMIC_RELAXED,
                                         __HIP_MEMORY_SCOPE_AGENT) < 32)
                    __builtin_amdgcn_s_sleep(1);
            __syncthreads();
            __builtin_amdgcn_fence(__ATOMIC_ACQUIRE, "agent");
            const short8* ha = (const short8*)h0ring +
                               ((size_t)((t & 3) * 4 + mt) * 16) * 64;
            #pragma unroll
            for (int kt = 0; kt < 16; ++kt) {
                short8 a = ha[kt * 64 + l];
                #pragma unroll
                for (int g = 0; g < 4; ++g)
                    acc[g] = __builtin_amdgcn_mfma_f32_16x16x32_bf16(
                        a, ldsf[(g * 32 + kt) * 64 + l], acc[g], 0, 0, 0);
            }
        }

        // ---- epilogue: activations, cell update (registers), h write-back ----
        unsigned short* hw = layer ? h1ring : h0ring;
        int slot = layer ? (t & 1) : (t & 3);
        size_t hwbase = ((size_t)(slot * 4 + mt) * 16) * 512 + hw_sub;
        #pragma unroll
        for (int r = 0; r < 4; ++r) {
            int m = q * 4 + r;
            int b = mt * 16 + m;
            float iv = fsigmoid(acc[0][r]);
            float fv = fsigmoid(acc[1][r]);
            float gv = ftanh(acc[2][r]);
            float ov = fsigmoid(acc[3][r]);
            float c = fv * cc[r] + iv * gv;
            cc[r] = c;
            float h = ov * ftanh(c);
            hw[hwbase + (size_t)(m + la_off) * 8] = f2bf(h);
            if (layer == 1) out[((size_t)b * HT + t) * HH + u] = h;
            if (t == HT - 1) {
                out[33554432 + layer * 32768 + b * 512 + u] = h;   // hidden
                out[33619968 + layer * 32768 + b * 512 + u] = c;   // cell
            }
        }

        __threadfence();
        __syncthreads();
        if (tid == 0) {
            int* fl = layer ? flag1 : flag0;
            __hip_atomic_fetch_add(&fl[t], 1, __ATOMIC_RELEASE,
                                   __HIP_MEMORY_SCOPE_AGENT);
        }
    }
}

extern "C" void kernel_launch(void* const* d_in, const int* in_sizes, int n_in,
                              void* d_out, int out_size, void* d_ws, size_t ws_size,
                              hipStream_t stream) {
    const float* x    = (const float*)d_in[0];
    const float* Wih0 = (const float*)d_in[1];
    const float* Whh0 = (const float*)d_in[2];
    const float* bih0 = (const float*)d_in[3];
    const float* bhh0 = (const float*)d_in[4];
    const float* Wih1 = (const float*)d_in[5];
    const float* Whh1 = (const float*)d_in[6];
    const float* bih1 = (const float*)d_in[7];
    const float* bhh1 = (const float*)d_in[8];

    char* ws = (char*)d_ws;
    // ws layout (bytes):
    //   wp0:    0          .. 3,145,728
    //   wp1:    3,145,728  .. 7,340,032
    //   bs:     7,340,032  .. 7,356,416
    //   xp:     7,356,416  .. 40,910,848
    //   flag0:  40,910,848 .. 40,914,944   (1024 int)
    //   flag1:  40,914,944 .. 40,919,040   (1024 int)
    //   h0ring: 40,919,040 .. 41,181,184   (4 slots x 64 KB)
    //   h1ring: 41,181,184 .. 41,312,256   (2 slots x 64 KB)
    unsigned short* wp0 = (unsigned short*)(ws + 0);
    unsigned short* wp1 = (unsigned short*)(ws + 3145728);
    float*          bsv = (float*)(ws + 7340032);
    unsigned short* xp  = (unsigned short*)(ws + 7356416);
    int*   flag0        = (int*)(ws + 40910848);
    int*   flag1        = (int*)(ws + 40914944);
    unsigned short* h0r = (unsigned short*)(ws + 40919040);
    unsigned short* h1r = (unsigned short*)(ws + 41181184);
    float* out = (float*)d_out;

    pack_weights<<<2048, 256, 0, stream>>>(Wih0, Whh0, bih0, bhh0,
                                           Wih1, Whh1, bih1, bhh1, wp0, wp1, bsv);
    pack_x<<<dim3(64, 8, 4), 256, 0, stream>>>(x, xp);
    init_flags<<<8, 256, 0, stream>>>(flag0, 2048);

    lstm_persist<<<64, 256, 0, stream>>>(wp0, wp1, bsv, xp, h0r, h1r,
                                         flag0, flag1, out);
}

// Round 3
// 7210.339 us; speedup vs baseline: 2.2163x; 2.2163x over previous
//
#include <hip/hip_runtime.h>

#define HB 64      // batch
#define HT 1024    // time
#define HI 256     // input dim
#define HH 512     // hidden dim

typedef short short8 __attribute__((ext_vector_type(8)));
typedef float f32x4 __attribute__((ext_vector_type(4)));

__device__ __forceinline__ unsigned short f2bf(float f) {
    unsigned u = __float_as_uint(f);
    u += 0x7FFF + ((u >> 16) & 1);          // round-to-nearest-even
    return (unsigned short)(u >> 16);
}
__device__ __forceinline__ float bf2f(unsigned short s) {
    return __uint_as_float(((unsigned)s) << 16);
}
__device__ __forceinline__ float fsigmoid(float x) {
    return __builtin_amdgcn_rcpf(1.0f + __expf(-x));
}
__device__ __forceinline__ float ftanh(float x) {
    return 1.0f - 2.0f * __builtin_amdgcn_rcpf(__expf(2.0f * x) + 1.0f);
}

// Coherent (L1/L2-bypassing) 16B fragment load as 2x8B relaxed agent atomics.
__device__ __forceinline__ short8 ld_frag(const unsigned long long* p) {
    union { unsigned long long u[2]; short8 s; } cv;
    cv.u[0] = __hip_atomic_load(p,     __ATOMIC_RELAXED, __HIP_MEMORY_SCOPE_AGENT);
    cv.u[1] = __hip_atomic_load(p + 1, __ATOMIC_RELAXED, __HIP_MEMORY_SCOPE_AGENT);
    return cv.s;
}

// ---------------------------------------------------------------------------
// Pack weights to bf16 in MFMA B-fragment-linear layout (proven round 1).
// ---------------------------------------------------------------------------
__global__ void pack_weights(const float* __restrict__ Wih0, const float* __restrict__ Whh0,
                             const float* __restrict__ bih0, const float* __restrict__ bhh0,
                             const float* __restrict__ Wih1, const float* __restrict__ Whh1,
                             const float* __restrict__ bih1, const float* __restrict__ bhh1,
                             unsigned short* __restrict__ wp0,
                             unsigned short* __restrict__ wp1,
                             float* __restrict__ bs) {
    int idx = blockIdx.x * 256 + threadIdx.x;
    int stride = gridDim.x * 256;
    const int NP0 = 128 * 24 * 512;
    const int NP1 = 128 * 32 * 512;
    for (int e = idx; e < NP0; e += stride) {
        int j = e & 7, l = (e >> 3) & 63, rem = e >> 9;
        int kt = rem % 24, nt = rem / 24;
        int n = nt * 16 + (l & 15);
        int k = kt * 32 + ((l >> 4) << 3) + j;
        float v = (k < HI) ? Wih0[n * HI + k] : Whh0[n * HH + (k - HI)];
        wp0[e] = f2bf(v);
    }
    for (int e = idx; e < NP1; e += stride) {
        int j = e & 7, l = (e >> 3) & 63, rem = e >> 9;
        int kt = rem & 31, nt = rem >> 5;
        int n = nt * 16 + (l & 15);
        int k = kt * 32 + ((l >> 4) << 3) + j;
        float v = (k < HH) ? Wih1[n * HH + k] : Whh1[n * HH + (k - HH)];
        wp1[e] = f2bf(v);
    }
    for (int e = idx; e < 2048; e += stride) {
        bs[e]        = bih0[e] + bhh0[e];
        bs[2048 + e] = bih1[e] + bhh1[e];
    }
}

// ---------------------------------------------------------------------------
// Pack x (B,1,I,T) -> bf16 A-fragment layout xp[t][mt(4)][kt(8)][lane(64)][j(8)]
// ---------------------------------------------------------------------------
__global__ void pack_x(const float* __restrict__ x, unsigned short* __restrict__ xp) {
    int tt = blockIdx.x;   // 64
    int ii = blockIdx.y;   // 8
    int bt = blockIdx.z;   // 4
    int w  = threadIdx.x;  // 256
    __shared__ unsigned short tile[512][16];
    int tloc = w & 15;
    for (int q = 0; q < 32; ++q) {
        int p = q * 16 + (w >> 4);
        int m = p >> 5, iloc = p & 31;
        int b = bt * 16 + m, i = ii * 32 + iloc, t = tt * 16 + tloc;
        tile[p][tloc] = f2bf(x[((size_t)b * HI + i) * HT + t]);
    }
    __syncthreads();
    int e  = w * 2;
    int l  = e >> 3, j0 = e & 7;
    int m  = l & 15;
    int i0 = ((l >> 4) << 3) + j0;
    for (int ti = 0; ti < 16; ++ti) {
        int t = tt * 16 + ti;
        size_t base = ((size_t)(t * 4 + bt) * 8 + ii) * 512;
        unsigned v0 = tile[m * 32 + i0][ti];
        unsigned v1 = tile[m * 32 + i0 + 1][ti];
        ((unsigned int*)xp)[(base + e) >> 1] = v0 | (v1 << 16);
    }
}

__global__ void init_flags(int* __restrict__ f, int n) {
    int idx = blockIdx.x * 256 + threadIdx.x;
    for (int e = idx; e < n; e += gridDim.x * 256) f[e] = 0;
}

// ---------------------------------------------------------------------------
// Persistent pipelined LSTM — FENCE-FREE.
// 64 blocks x 256 threads, 1 block/CU (128 KB LDS weights + 2 KB h stage).
// Blocks 0..31: layer0 (ut).  Blocks 32..63: layer1 (ut).
// Data exchange: h rings written/read with relaxed AGENT-scope atomics
// (sc0/sc1 cache-bypassing) -> no buffer_wbl2 / buffer_inv ever.
// Sync: per-block flags flagX[t*32+ut] (store 1), consumer polls 32 lanes +
// ballot. Producer order: coherent ring stores -> s_waitcnt vmcnt(0) ->
// barrier -> flag store.  Dependencies:
//   layer0 step t:  flag0[t-1], flag1[t-8]  (h0 ring depth 8)
//   layer1 step t:  flag1[t-1], flag0[t]    (h1 ring depth 2)
// ---------------------------------------------------------------------------
__global__ void __launch_bounds__(256, 1) lstm_persist(
        const unsigned short* __restrict__ wp0,
        const unsigned short* __restrict__ wp1,
        const float* __restrict__ bs,
        const unsigned short* __restrict__ xp,
        unsigned long long* __restrict__ h0ring,   // [8][mt4][kt16][64][8] bf16
        unsigned long long* __restrict__ h1ring,   // [2][mt4][kt16][64][8] bf16
        int* __restrict__ flag0,
        int* __restrict__ flag1,
        float* __restrict__ out) {
    __shared__ int4 ldsw[8192];                 // 128 KB weight slice
    __shared__ unsigned long long stage[256];   // 2 KB h staging

    const int bid   = blockIdx.x;
    const int layer = bid >> 5;
    const int ut    = bid & 31;
    const int tid   = threadIdx.x;
    const int mt    = tid >> 6;
    const int l     = tid & 63;
    const int ul    = l & 15;
    const int q     = l >> 4;
    const int KT    = layer ? 32 : 24;

    const short8* ldsf = (const short8*)ldsw;
    unsigned short* stage_s = (unsigned short*)stage;

    // ---- stage weight slice into LDS ----
    {
        const unsigned short* wsrc = layer ? wp1 : wp0;
        for (int g = 0; g < 4; ++g) {
            const int4* src = (const int4*)(wsrc + (size_t)(g * 32 + ut) * KT * 512);
            int4* dst = ldsw + (size_t)g * KT * 64;
            for (int i = tid; i < KT * 64; i += 256) dst[i] = src[i];
        }
    }
    float bv[4];
    #pragma unroll
    for (int g = 0; g < 4; ++g) bv[g] = bs[layer * 2048 + g * HH + ut * 16 + ul];
    float cc[4] = {0.f, 0.f, 0.f, 0.f};
    __syncthreads();

    const int u = ut * 16 + ul;
    const int stg_w = mt * 256 + (ul >> 3) * 128 + (ul & 7);  // + m*8 at use
    const size_t ring_dst_sub = (size_t)(tid >> 6) * 2048 +
                                (ut >> 1) * 128 + ((2 * ut) & 3) * 32 + (tid & 63);

    for (int t = 0; t < HT; ++t) {
        f32x4 acc[4];
        #pragma unroll
        for (int g = 0; g < 4; ++g) {
            f32x4 a; a[0] = bv[g]; a[1] = bv[g]; a[2] = bv[g]; a[3] = bv[g];
            acc[g] = a;
        }

        if (layer == 0) {
            // x part first: no dependency, overlaps the spin below
            const short8* xa = (const short8*)xp + ((size_t)t * 4 + mt) * 8 * 64;
            #pragma unroll
            for (int kt = 0; kt < 8; ++kt) {
                short8 a = xa[kt * 64 + l];
                #pragma unroll
                for (int g = 0; g < 4; ++g)
                    acc[g] = __builtin_amdgcn_mfma_f32_16x16x32_bf16(
                        a, ldsf[(g * 24 + kt) * 64 + l], acc[g], 0, 0, 0);
            }
            if (t > 0) {
                if (tid < 64) {   // wave 0 polls: lanes 0-31 flag0[t-1], 32-63 flag1[t-8]
                    const int* p;
                    bool skip;
                    if (l < 32) { p = flag0 + (size_t)(t - 1) * 32 + l; skip = false; }
                    else        { p = flag1 + (size_t)(t >= 8 ? t - 8 : 0) * 32 + (l - 32);
                                  skip = (t < 8); }
                    for (;;) {
                        int v = skip ? 1 : __hip_atomic_load(p, __ATOMIC_RELAXED,
                                                             __HIP_MEMORY_SCOPE_AGENT);
                        if (__ballot(v != 0) == ~0ull) break;
                        __builtin_amdgcn_s_sleep(1);
                    }
                }
                __syncthreads();
                const unsigned long long* hb =
                    h0ring + ((size_t)(((t - 1) & 7) * 4 + mt)) * 2048;
                short8 af[16];
                #pragma unroll
                for (int kt = 0; kt < 16; ++kt) af[kt] = ld_frag(hb + kt * 128 + l * 2);
                #pragma unroll
                for (int kt = 0; kt < 16; ++kt) {
                    #pragma unroll
                    for (int g = 0; g < 4; ++g)
                        acc[g] = __builtin_amdgcn_mfma_f32_16x16x32_bf16(
                            af[kt], ldsf[(g * 24 + 8 + kt) * 64 + l], acc[g], 0, 0, 0);
                }
            }
        } else {
            if (t > 0) {   // recurrent half: needs flag1[t-1]
                if (tid < 64) {
                    const int* p = flag1 + (size_t)(t - 1) * 32 + (l & 31);
                    while (__ballot(__hip_atomic_load(p, __ATOMIC_RELAXED,
                                    __HIP_MEMORY_SCOPE_AGENT) != 0) != ~0ull)
                        __builtin_amdgcn_s_sleep(1);
                }
                __syncthreads();
                const unsigned long long* hb =
                    h1ring + ((size_t)(((t - 1) & 1) * 4 + mt)) * 2048;
                short8 af[16];
                #pragma unroll
                for (int kt = 0; kt < 16; ++kt) af[kt] = ld_frag(hb + kt * 128 + l * 2);
                #pragma unroll
                for (int kt = 0; kt < 16; ++kt) {
                    #pragma unroll
                    for (int g = 0; g < 4; ++g)
                        acc[g] = __builtin_amdgcn_mfma_f32_16x16x32_bf16(
                            af[kt], ldsf[(g * 32 + 16 + kt) * 64 + l], acc[g], 0, 0, 0);
                }
            }
            // input half: needs flag0[t]
            if (tid < 64) {
                const int* p = flag0 + (size_t)t * 32 + (l & 31);
                while (__ballot(__hip_atomic_load(p, __ATOMIC_RELAXED,
                                __HIP_MEMORY_SCOPE_AGENT) != 0) != ~0ull)
                    __builtin_amdgcn_s_sleep(1);
            }
            __syncthreads();
            const unsigned long long* hb =
                h0ring + ((size_t)((t & 7) * 4 + mt)) * 2048;
            short8 af[16];
            #pragma unroll
            for (int kt = 0; kt < 16; ++kt) af[kt] = ld_frag(hb + kt * 128 + l * 2);
            #pragma unroll
            for (int kt = 0; kt < 16; ++kt) {
                #pragma unroll
                for (int g = 0; g < 4; ++g)
                    acc[g] = __builtin_amdgcn_mfma_f32_16x16x32_bf16(
                        af[kt], ldsf[(g * 32 + kt) * 64 + l], acc[g], 0, 0, 0);
            }
        }

        // ---- epilogue: activations, cell update (registers), stage h ----
        #pragma unroll
        for (int r = 0; r < 4; ++r) {
            int m = q * 4 + r;
            int b = mt * 16 + m;
            float iv = fsigmoid(acc[0][r]);
            float fv = fsigmoid(acc[1][r]);
            float gv = ftanh(acc[2][r]);
            float ov = fsigmoid(acc[3][r]);
            float c = fv * cc[r] + iv * gv;
            cc[r] = c;
            float h = ov * ftanh(c);
            stage_s[stg_w + m * 8] = f2bf(h);
            if (t == HT - 1) {
                out[33554432 + layer * 32768 + b * 512 + u] = h;   // hidden
                out[33619968 + layer * 32768 + b * 512 + u] = c;   // cell
            }
        }
        __syncthreads();

        // ---- coherent ring store (1x8B per thread, coalesced) ----
        {
            unsigned long long v = stage[tid];
            unsigned long long* ring = layer ? h1ring : h0ring;
            int slot = layer ? (t & 1) : (t & 7);
            __hip_atomic_store(ring + (size_t)slot * 8192 + ring_dst_sub, v,
                               __ATOMIC_RELAXED, __HIP_MEMORY_SCOPE_AGENT);
        }
        // layer1: sequence output from stage (cached float4 stores)
        if (layer == 1) {
            int b = tid >> 2, ch = tid & 3;
            const unsigned short* sp = stage_s + (b >> 4) * 256 + (ch >> 1) * 128 +
                                       (b & 15) * 8 + (ch & 1) * 4;
            f32x4 o;
            o[0] = bf2f(sp[0]); o[1] = bf2f(sp[1]);
            o[2] = bf2f(sp[2]); o[3] = bf2f(sp[3]);
            *(f32x4*)&out[((size_t)b * HT + t) * HH + ut * 16 + ch * 4] = o;
        }

        asm volatile("s_waitcnt vmcnt(0)" ::: "memory");
        __syncthreads();
        if (tid == 0) {
            int* fl = layer ? flag1 : flag0;
            __hip_atomic_store(fl + (size_t)t * 32 + ut, 1,
                               __ATOMIC_RELAXED, __HIP_MEMORY_SCOPE_AGENT);
        }
    }
}

extern "C" void kernel_launch(void* const* d_in, const int* in_sizes, int n_in,
                              void* d_out, int out_size, void* d_ws, size_t ws_size,
                              hipStream_t stream) {
    const float* x    = (const float*)d_in[0];
    const float* Wih0 = (const float*)d_in[1];
    const float* Whh0 = (const float*)d_in[2];
    const float* bih0 = (const float*)d_in[3];
    const float* bhh0 = (const float*)d_in[4];
    const float* Wih1 = (const float*)d_in[5];
    const float* Whh1 = (const float*)d_in[6];
    const float* bih1 = (const float*)d_in[7];
    const float* bhh1 = (const float*)d_in[8];

    char* ws = (char*)d_ws;
    // ws layout (bytes):
    //   wp0:    0          .. 3,145,728
    //   wp1:    3,145,728  .. 7,340,032
    //   bs:     7,340,032  .. 7,356,416
    //   xp:     7,356,416  .. 40,910,848
    //   flag0:  40,910,848 .. 41,041,920   (1024*32 int)
    //   flag1:  41,041,920 .. 41,172,992   (1024*32 int)
    //   h0ring: 41,172,992 .. 41,697,280   (8 slots x 64 KB)
    //   h1ring: 41,697,280 .. 41,828,352   (2 slots x 64 KB)
    unsigned short* wp0 = (unsigned short*)(ws + 0);
    unsigned short* wp1 = (unsigned short*)(ws + 3145728);
    float*          bsv = (float*)(ws + 7340032);
    unsigned short* xp  = (unsigned short*)(ws + 7356416);
    int*   flag0        = (int*)(ws + 40910848);
    int*   flag1        = (int*)(ws + 41041920);
    unsigned long long* h0r = (unsigned long long*)(ws + 41172992);
    unsigned long long* h1r = (unsigned long long*)(ws + 41697280);
    float* out = (float*)d_out;

    pack_weights<<<2048, 256, 0, stream>>>(Wih0, Whh0, bih0, bhh0,
                                           Wih1, Whh1, bih1, bhh1, wp0, wp1, bsv);
    pack_x<<<dim3(64, 8, 4), 256, 0, stream>>>(x, xp);
    init_flags<<<64, 256, 0, stream>>>(flag0, 65536);

    lstm_persist<<<64, 256, 0, stream>>>(wp0, wp1, bsv, xp, h0r, h1r,
                                         flag0, flag1, out);
}